// Round 1
// baseline (587.440 us; speedup 1.0000x reference)
//
#include <hip/hip_runtime.h>

// MHA forward: B=2, T=2048, DIM=1024, NH=16, HD=64
// Pipeline: [qkv_rope GEMM] -> ws{Q,K bf16 [B,NH,T,HD], V^T bf16 [B,NH,HD,T]}
//           [flash attn]    -> ws{Y bf16 [B,T,DIM]}
//           [proj GEMM]     -> d_out fp32 [B,T,DIM]

typedef float  f32x4  __attribute__((ext_vector_type(4)));
typedef __bf16 bf16x8 __attribute__((ext_vector_type(8)));
typedef short  short8 __attribute__((ext_vector_type(8)));
typedef short  short4v __attribute__((ext_vector_type(4)));

#define Bb   2
#define Tt   2048
#define DIMc 1024
#define NHh  16
#define HDd  64

__device__ __forceinline__ short f2bf(float f) {
    unsigned u = __builtin_bit_cast(unsigned, f);
    u += 0x7fffu + ((u >> 16) & 1u);          // round-to-nearest-even
    return (short)(u >> 16);
}

__device__ __forceinline__ f32x4 mfma16(short8 a, short8 b, f32x4 c) {
    return __builtin_amdgcn_mfma_f32_16x16x32_bf16(
        __builtin_bit_cast(bf16x8, a), __builtin_bit_cast(bf16x8, b), c, 0, 0, 0);
}

// ---------------------------------------------------------------------------
// Kernel 1: qkv = x @ W_qkv  (M=4096, N=3072, K=1024), fused RoPE epilogue.
// 64x64 tile / block, 4 waves, each wave 32x32 (2x2 MFMA 16x16x32).
// A LDS: [m][k] row-major (frag reads contiguous in k).
// B LDS: [n][k] (transposed on store; frag reads contiguous in k).
// ---------------------------------------------------------------------------
__global__ __launch_bounds__(256) void qkv_rope(
    const float* __restrict__ X, const float* __restrict__ W,
    const float* __restrict__ Sn, const float* __restrict__ Cs,
    short* __restrict__ Qo, short* __restrict__ Ko, short* __restrict__ Vt)
{
    __shared__ __align__(16) short As[64][32];
    __shared__ __align__(16) short Bs[64][32];
    const int bm = blockIdx.x, bn = blockIdx.y;
    const int tid = threadIdx.x;
    const int wv = tid >> 6, lane = tid & 63, g = lane >> 4, l16 = lane & 15;
    const int wr = wv >> 1, wc = wv & 1;

    f32x4 acc[2][2];
#pragma unroll
    for (int i = 0; i < 2; i++)
#pragma unroll
        for (int j = 0; j < 2; j++) acc[i][j] = (f32x4){0.f, 0.f, 0.f, 0.f};

    for (int k0 = 0; k0 < 1024; k0 += 32) {
#pragma unroll
        for (int i = 0; i < 2; i++) {              // A tile 64x32 fp32 -> bf16
            int p = tid + i * 256;
            int r = p >> 3, c = (p & 7) << 2;
            float4 v = *(const float4*)(X + (size_t)(bm * 64 + r) * 1024 + k0 + c);
            short4v s;
            s.x = f2bf(v.x); s.y = f2bf(v.y); s.z = f2bf(v.z); s.w = f2bf(v.w);
            *(short4v*)&As[r][c] = s;
        }
#pragma unroll
        for (int i = 0; i < 2; i++) {              // B tile 32x64 fp32 -> bf16 (transpose)
            int p = tid + i * 256;
            int kk = p >> 4, c = (p & 15) << 2;
            float4 v = *(const float4*)(W + (size_t)(k0 + kk) * 3072 + bn * 64 + c);
            Bs[c + 0][kk] = f2bf(v.x); Bs[c + 1][kk] = f2bf(v.y);
            Bs[c + 2][kk] = f2bf(v.z); Bs[c + 3][kk] = f2bf(v.w);
        }
        __syncthreads();
        short8 af[2], bfr[2];
#pragma unroll
        for (int mt = 0; mt < 2; mt++) af[mt] = *(const short8*)&As[wr * 32 + mt * 16 + l16][g * 8];
#pragma unroll
        for (int nt = 0; nt < 2; nt++) bfr[nt] = *(const short8*)&Bs[wc * 32 + nt * 16 + l16][g * 8];
#pragma unroll
        for (int mt = 0; mt < 2; mt++)
#pragma unroll
            for (int nt = 0; nt < 2; nt++) acc[mt][nt] = mfma16(af[mt], bfr[nt], acc[mt][nt]);
        __syncthreads();
    }

    // Epilogue: C row m = token index, col n in [0,3072). RoPE on q/k, V transposed.
#pragma unroll
    for (int mt = 0; mt < 2; mt++)
#pragma unroll
        for (int nt = 0; nt < 2; nt++)
#pragma unroll
            for (int r = 0; r < 4; r++) {
                int m = bm * 64 + wr * 32 + mt * 16 + g * 4 + r;
                int n = bn * 64 + wc * 32 + nt * 16 + l16;
                float val = acc[mt][nt][r];
                float partner = __shfl_xor(val, 1, 64);   // pair element (d^1)
                int b = m >> 11, t = m & 2047;
                int sec = n >> 10, nn = n & 1023;
                int h = nn >> 6, d = nn & 63;
                if (sec == 2) {
                    Vt[(((size_t)(b * 16 + h) * 64 + d) << 11) + t] = f2bf(val);
                } else {
                    float sv = Sn[t * 64 + d], cv = Cs[t * 64 + d];
                    float ro = (d & 1) ? fmaf(val, cv, partner * sv)
                                       : fmaf(val, cv, -partner * sv);
                    short* dst = (sec == 0) ? Qo : Ko;
                    dst[(((size_t)(b * 16 + h) << 11) + t) * 64 + d] = f2bf(ro);
                }
            }
}

// ---------------------------------------------------------------------------
// Kernel 2: causal flash attention. Grid (T/64, B*NH), 256 thr = 4 waves.
// Wave = 16 query rows; loop over 32-key steps with online softmax.
// Q/K frags direct from global ([B,NH,T,HD], contiguous in head-dim = MFMA k).
// V frags direct from global V^T ([B,NH,HD,T], contiguous in key = MFMA k).
// P: C-layout -> A-layout via per-wave LDS round trip.
// ---------------------------------------------------------------------------
__global__ __launch_bounds__(256) void attn(
    const short* __restrict__ Q, const short* __restrict__ K,
    const short* __restrict__ V, short* __restrict__ Y)
{
    __shared__ __align__(16) short Pl[4][16][32];
    const int bh = blockIdx.y;
    const int tid = threadIdx.x, wv = tid >> 6, lane = tid & 63;
    const int g = lane >> 4, l16 = lane & 15;
    const int q0 = blockIdx.x * 64 + wv * 16;
    const short* Qb = Q + (size_t)bh * Tt * 64;
    const short* Kb = K + (size_t)bh * Tt * 64;
    const short* Vb = V + (size_t)bh * 64 * Tt;

    short8 qf[2];
#pragma unroll
    for (int s = 0; s < 2; s++)
        qf[s] = *(const short8*)(Qb + (size_t)(q0 + l16) * 64 + s * 32 + g * 8);

    f32x4 o[4];
#pragma unroll
    for (int nt = 0; nt < 4; nt++) o[nt] = (f32x4){0.f, 0.f, 0.f, 0.f};
    float mi[4] = {-3e38f, -3e38f, -3e38f, -3e38f};
    float li[4] = {0.f, 0.f, 0.f, 0.f};

    for (int k0 = 0; k0 < q0 + 16; k0 += 32) {
        f32x4 S[2];
#pragma unroll
        for (int t = 0; t < 2; t++) {
            S[t] = (f32x4){0.f, 0.f, 0.f, 0.f};
#pragma unroll
            for (int s = 0; s < 2; s++) {
                short8 kf = *(const short8*)(Kb + (size_t)(k0 + t * 16 + l16) * 64 + s * 32 + g * 8);
                S[t] = mfma16(qf[s], kf, S[t]);
            }
        }
        float p[2][4];
#pragma unroll
        for (int r = 0; r < 4; r++) {
            int qq = q0 + g * 4 + r;
            float s0 = (k0 + l16      <= qq) ? S[0][r] * 0.125f : -INFINITY;
            float s1 = (k0 + 16 + l16 <= qq) ? S[1][r] * 0.125f : -INFINITY;
            float mt = fmaxf(s0, s1);
            mt = fmaxf(mt, __shfl_xor(mt, 1, 16));
            mt = fmaxf(mt, __shfl_xor(mt, 2, 16));
            mt = fmaxf(mt, __shfl_xor(mt, 4, 16));
            mt = fmaxf(mt, __shfl_xor(mt, 8, 16));
            float mn = fmaxf(mi[r], mt);
            float al = __expf(mi[r] - mn);
            float p0 = __expf(s0 - mn), p1 = __expf(s1 - mn);
            float ps = p0 + p1;
            ps += __shfl_xor(ps, 1, 16);
            ps += __shfl_xor(ps, 2, 16);
            ps += __shfl_xor(ps, 4, 16);
            ps += __shfl_xor(ps, 8, 16);
            li[r] = li[r] * al + ps;
            mi[r] = mn;
            p[0][r] = p0; p[1][r] = p1;
#pragma unroll
            for (int nt = 0; nt < 4; nt++) o[nt][r] *= al;
        }
        // P: C-layout (row=g*4+r, col=t*16+l16) -> LDS row-major [query][key]
#pragma unroll
        for (int t = 0; t < 2; t++)
#pragma unroll
            for (int r = 0; r < 4; r++)
                Pl[wv][g * 4 + r][t * 16 + l16] = f2bf(p[t][r]);
        asm volatile("" ::: "memory");   // keep ds_read after ds_writes (per-wave, in-order DS)
        short8 pf = *(const short8*)&Pl[wv][l16][g * 8];
#pragma unroll
        for (int nt = 0; nt < 4; nt++) {
            short8 vf = *(const short8*)(Vb + (size_t)(nt * 16 + l16) * Tt + k0 + g * 8);
            o[nt] = mfma16(pf, vf, o[nt]);
        }
    }

    const int b = bh >> 4, h = bh & 15;
#pragma unroll
    for (int nt = 0; nt < 4; nt++)
#pragma unroll
        for (int r = 0; r < 4; r++) {
            int qq = q0 + g * 4 + r;
            int d = nt * 16 + l16;
            float inv = 1.0f / li[r];
            Y[((size_t)(b * Tt + qq)) * DIMc + h * 64 + d] = f2bf(o[nt][r] * inv);
        }
}

// ---------------------------------------------------------------------------
// Kernel 3: out = Y @ W_proj  (M=4096, N=1024, K=1024), fp32 output.
// ---------------------------------------------------------------------------
__global__ __launch_bounds__(256) void proj(
    const short* __restrict__ Yb, const float* __restrict__ W, float* __restrict__ O)
{
    __shared__ __align__(16) short As[64][32];
    __shared__ __align__(16) short Bs[64][32];
    const int bm = blockIdx.x, bn = blockIdx.y;
    const int tid = threadIdx.x;
    const int wv = tid >> 6, lane = tid & 63, g = lane >> 4, l16 = lane & 15;
    const int wr = wv >> 1, wc = wv & 1;

    f32x4 acc[2][2];
#pragma unroll
    for (int i = 0; i < 2; i++)
#pragma unroll
        for (int j = 0; j < 2; j++) acc[i][j] = (f32x4){0.f, 0.f, 0.f, 0.f};

    for (int k0 = 0; k0 < 1024; k0 += 32) {
        {   // A tile 64x32 bf16: one short8 per thread
            int r = tid >> 2, c = (tid & 3) << 3;
            *(short8*)&As[r][c] = *(const short8*)(Yb + (size_t)(bm * 64 + r) * 1024 + k0 + c);
        }
#pragma unroll
        for (int i = 0; i < 2; i++) {              // B tile 32x64 fp32 -> bf16 (transpose)
            int p = tid + i * 256;
            int kk = p >> 4, c = (p & 15) << 2;
            float4 v = *(const float4*)(W + (size_t)(k0 + kk) * 1024 + bn * 64 + c);
            Bs[c + 0][kk] = f2bf(v.x); Bs[c + 1][kk] = f2bf(v.y);
            Bs[c + 2][kk] = f2bf(v.z); Bs[c + 3][kk] = f2bf(v.w);
        }
        __syncthreads();
        short8 af[2], bfr[2];
#pragma unroll
        for (int mt = 0; mt < 2; mt++) af[mt] = *(const short8*)&As[wr * 32 + mt * 16 + l16][g * 8];
#pragma unroll
        for (int nt = 0; nt < 2; nt++) bfr[nt] = *(const short8*)&Bs[wc * 32 + nt * 16 + l16][g * 8];
#pragma unroll
        for (int mt = 0; mt < 2; mt++)
#pragma unroll
            for (int nt = 0; nt < 2; nt++) acc[mt][nt] = mfma16(af[mt], bfr[nt], acc[mt][nt]);
        __syncthreads();
    }

#pragma unroll
    for (int mt = 0; mt < 2; mt++)
#pragma unroll
        for (int nt = 0; nt < 2; nt++)
#pragma unroll
            for (int r = 0; r < 4; r++) {
                int m = bm * 64 + wr * 32 + mt * 16 + g * 4 + r;
                int n = bn * 64 + wc * 32 + nt * 16 + l16;
                O[(size_t)m * 1024 + n] = acc[mt][nt][r];
            }
}

// ---------------------------------------------------------------------------
extern "C" void kernel_launch(void* const* d_in, const int* in_sizes, int n_in,
                              void* d_out, int out_size, void* d_ws, size_t ws_size,
                              hipStream_t stream)
{
    const float* x     = (const float*)d_in[0];
    const float* sn    = (const float*)d_in[1];
    const float* cs    = (const float*)d_in[2];
    const float* wqkv  = (const float*)d_in[3];
    const float* wproj = (const float*)d_in[4];
    float* out = (float*)d_out;

    char* ws = (char*)d_ws;
    const size_t SEG = (size_t)Bb * NHh * Tt * HDd * sizeof(short);  // 8 MB
    short* q  = (short*)(ws);
    short* k  = (short*)(ws + SEG);
    short* vt = (short*)(ws + 2 * SEG);
    short* y  = (short*)(ws + 3 * SEG);

    qkv_rope<<<dim3(64, 48), 256, 0, stream>>>(x, wqkv, sn, cs, q, k, vt);
    attn<<<dim3(Tt / 64, Bb * NHh), 256, 0, stream>>>(q, k, vt, y);
    proj<<<dim3(64, 16), 256, 0, stream>>>(y, wproj, out);
}

// Round 2
// 423.964 us; speedup vs baseline: 1.3856x; 1.3856x over previous
//
#include <hip/hip_runtime.h>

// MHA forward: B=2, T=2048, DIM=1024, NH=16, HD=64
// [qkv_rope 128x128 GEMM] -> ws{Q,K bf16 [B,NH,T,HD], V^T bf16 [B,NH,HD,T]}
// [flash attn, LDS-staged K/V dbuf] -> ws{Y bf16 [B,T,DIM]}
// [proj 128x128 GEMM] -> d_out fp32

typedef float  f32x4  __attribute__((ext_vector_type(4)));
typedef __bf16 bf16x8 __attribute__((ext_vector_type(8)));
typedef short  short8 __attribute__((ext_vector_type(8)));
typedef short  short4v __attribute__((ext_vector_type(4)));

#define Bb   2
#define Tt   2048
#define DIMc 1024
#define NHh  16
#define HDd  64

__device__ __forceinline__ short f2bf(float f) {
    unsigned u = __builtin_bit_cast(unsigned, f);
    u += 0x7fffu + ((u >> 16) & 1u);          // RNE
    return (short)(u >> 16);
}

__device__ __forceinline__ f32x4 mfma16(short8 a, short8 b, f32x4 c) {
    return __builtin_amdgcn_mfma_f32_16x16x32_bf16(
        __builtin_bit_cast(bf16x8, a), __builtin_bit_cast(bf16x8, b), c, 0, 0, 0);
}

__device__ __forceinline__ void gl_lds16(const void* g, void* l) {
    __builtin_amdgcn_global_load_lds(
        (const __attribute__((address_space(1))) unsigned int*)g,
        (__attribute__((address_space(3))) unsigned int*)l, 16, 0, 0);
}

// ---------------------------------------------------------------------------
// Kernel 1: qkv = x @ W_qkv (M=4096,N=3072,K=1024), fused RoPE.
// 128x128 tile, 4 waves, each 64x64 (4x4 MFMA 16x16x32).
// ---------------------------------------------------------------------------
__global__ __launch_bounds__(256) void qkv_rope(
    const float* __restrict__ X, const float* __restrict__ W,
    const float* __restrict__ Sn, const float* __restrict__ Cs,
    short* __restrict__ Qo, short* __restrict__ Ko, short* __restrict__ Vt)
{
    __shared__ __align__(16) short As[128][32];
    __shared__ __align__(16) short Bs[128][32];
    const int bm = blockIdx.x, bn = blockIdx.y;
    const int tid = threadIdx.x;
    const int wv = tid >> 6, lane = tid & 63, g = lane >> 4, l16 = lane & 15;
    const int wr = wv >> 1, wc = wv & 1;

    f32x4 acc[4][4];
#pragma unroll
    for (int i = 0; i < 4; i++)
#pragma unroll
        for (int j = 0; j < 4; j++) acc[i][j] = (f32x4){0.f, 0.f, 0.f, 0.f};

    for (int k0 = 0; k0 < 1024; k0 += 32) {
#pragma unroll
        for (int i = 0; i < 4; i++) {              // A 128x32 fp32->bf16
            int p = tid + i * 256;
            int r = p >> 3, c = (p & 7) << 2;
            float4 v = *(const float4*)(X + (size_t)(bm * 128 + r) * 1024 + k0 + c);
            short4v s;
            s.x = f2bf(v.x); s.y = f2bf(v.y); s.z = f2bf(v.z); s.w = f2bf(v.w);
            *(short4v*)&As[r][c] = s;
        }
#pragma unroll
        for (int i = 0; i < 4; i++) {              // B 32x128 fp32->bf16 (transpose)
            int p = tid + i * 256;
            int kk = p >> 5, c = (p & 31) << 2;
            float4 v = *(const float4*)(W + (size_t)(k0 + kk) * 3072 + bn * 128 + c);
            Bs[c + 0][kk] = f2bf(v.x); Bs[c + 1][kk] = f2bf(v.y);
            Bs[c + 2][kk] = f2bf(v.z); Bs[c + 3][kk] = f2bf(v.w);
        }
        __syncthreads();
        short8 af[4], bfr[4];
#pragma unroll
        for (int mt = 0; mt < 4; mt++) af[mt]  = *(const short8*)&As[wr * 64 + mt * 16 + l16][g * 8];
#pragma unroll
        for (int nt = 0; nt < 4; nt++) bfr[nt] = *(const short8*)&Bs[wc * 64 + nt * 16 + l16][g * 8];
#pragma unroll
        for (int mt = 0; mt < 4; mt++)
#pragma unroll
            for (int nt = 0; nt < 4; nt++) acc[mt][nt] = mfma16(af[mt], bfr[nt], acc[mt][nt]);
        __syncthreads();
    }

#pragma unroll
    for (int mt = 0; mt < 4; mt++)
#pragma unroll
        for (int nt = 0; nt < 4; nt++)
#pragma unroll
            for (int r = 0; r < 4; r++) {
                int m = bm * 128 + wr * 64 + mt * 16 + g * 4 + r;
                int n = bn * 128 + wc * 64 + nt * 16 + l16;
                float val = acc[mt][nt][r];
                float partner = __shfl_xor(val, 1, 64);
                int b = m >> 11, t = m & 2047;
                int sec = n >> 10, nn = n & 1023;
                int h = nn >> 6, d = nn & 63;
                if (sec == 2) {
                    Vt[(((size_t)(b * 16 + h) * 64 + d) << 11) + t] = f2bf(val);
                } else {
                    float sv = Sn[t * 64 + d], cv = Cs[t * 64 + d];
                    float ro = (d & 1) ? fmaf(val, cv, partner * sv)
                                       : fmaf(val, cv, -partner * sv);
                    short* dst = (sec == 0) ? Qo : Ko;
                    dst[(((size_t)(b * 16 + h) << 11) + t) * 64 + d] = f2bf(ro);
                }
            }
}

// ---------------------------------------------------------------------------
// Kernel 2: causal flash attention.
// Block = 64 queries (4 waves x 16q), 64-key steps, K/V double-buffered in LDS
// via global_load_lds w16 with XOR chunk swizzle. Fixed-shift softmax
// (exp(s*scale - 10)), row-sum reduced once at the end.
// ---------------------------------------------------------------------------
__global__ __launch_bounds__(256, 4) void attn(
    const short* __restrict__ Q, const short* __restrict__ K,
    const short* __restrict__ V, short* __restrict__ Y)
{
    __shared__ __align__(16) short Ks[2][64][64];
    __shared__ __align__(16) short Vs[2][64][64];
    __shared__ __align__(16) short Pl[4][16][64];

    const int id = blockIdx.y * gridDim.x + blockIdx.x;
    const int bh = id >> 5;
    const int qi = ((id & 31) + ((id >> 8) << 3)) & 31;   // depth-balanced swizzle
    const int tid = threadIdx.x, wv = tid >> 6, lane = tid & 63;
    const int g = lane >> 4, l16 = lane & 15;
    const int q0b = qi * 64, q0w = q0b + wv * 16;
    const short* Qb = Q + (size_t)bh * Tt * 64;
    const short* Kb = K + (size_t)bh * Tt * 64;
    const short* Vb = V + (size_t)bh * 64 * Tt;

    const int rj = lane >> 3, cc = lane & 7, gc = cc ^ rj;  // staging lane map

    auto stage = [&](int s, int buf) {
        int k0s = s * 64;
#pragma unroll
        for (int j = 0; j < 2; j++) {
            int row = wv * 16 + j * 8 + rj;
            gl_lds16(Kb + (size_t)(k0s + row) * 64 + gc * 8, &Ks[buf][row][cc << 3]);
        }
#pragma unroll
        for (int j = 0; j < 2; j++) {
            int row = wv * 16 + j * 8 + rj;
            gl_lds16(Vb + (size_t)row * Tt + k0s + gc * 8, &Vs[buf][row][cc << 3]);
        }
    };

    short8 qf[2];
#pragma unroll
    for (int ss = 0; ss < 2; ss++)
        qf[ss] = *(const short8*)(Qb + (size_t)(q0w + l16) * 64 + ss * 32 + g * 8);

    f32x4 o[4];
#pragma unroll
    for (int nt = 0; nt < 4; nt++) o[nt] = (f32x4){0.f, 0.f, 0.f, 0.f};
    float lsum[4] = {0.f, 0.f, 0.f, 0.f};

    const int nsteps = qi + 1;
    const int sw = l16 & 7;                 // read-side XOR swizzle key

    stage(0, 0);
    __syncthreads();

    for (int s = 0; s < nsteps; ++s) {
        if (s + 1 < nsteps) stage(s + 1, (s + 1) & 1);
        const int kb = s & 1, k0 = s * 64;

        f32x4 S[4];
#pragma unroll
        for (int t = 0; t < 4; t++) {
            S[t] = (f32x4){0.f, 0.f, 0.f, 0.f};
#pragma unroll
            for (int ss = 0; ss < 2; ss++) {
                short8 kf = *(const short8*)&Ks[kb][t * 16 + l16][((ss * 4 + g) ^ sw) << 3];
                S[t] = mfma16(qf[ss], kf, S[t]);
            }
        }

        float p[4][4];
        if (s < nsteps - 1) {               // full (unmasked) step
#pragma unroll
            for (int t = 0; t < 4; t++)
#pragma unroll
                for (int r = 0; r < 4; r++)
                    p[t][r] = __expf(fmaf(S[t][r], 0.125f, -10.f));
        } else {                            // diagonal step: causal mask
#pragma unroll
            for (int t = 0; t < 4; t++)
#pragma unroll
                for (int r = 0; r < 4; r++) {
                    int key = k0 + t * 16 + l16, qq = q0w + g * 4 + r;
                    p[t][r] = (key <= qq) ? __expf(fmaf(S[t][r], 0.125f, -10.f)) : 0.f;
                }
        }
#pragma unroll
        for (int r = 0; r < 4; r++)
            lsum[r] += (p[0][r] + p[1][r]) + (p[2][r] + p[3][r]);

        // P: C-layout -> A-layout via LDS (swizzled cols)
#pragma unroll
        for (int t = 0; t < 4; t++)
#pragma unroll
            for (int r = 0; r < 4; r++) {
                int row = g * 4 + r, c = t * 16 + l16;
                Pl[wv][row][(((c >> 3) ^ (row & 7)) << 3) | (c & 7)] = f2bf(p[t][r]);
            }
        asm volatile("" ::: "memory");
        short8 pf[2];
#pragma unroll
        for (int ks = 0; ks < 2; ks++)
            pf[ks] = *(const short8*)&Pl[wv][l16][((ks * 4 + g) ^ sw) << 3];
#pragma unroll
        for (int nt = 0; nt < 4; nt++)
#pragma unroll
            for (int ks = 0; ks < 2; ks++) {
                short8 vf = *(const short8*)&Vs[kb][nt * 16 + l16][((ks * 4 + g) ^ sw) << 3];
                o[nt] = mfma16(pf[ks], vf, o[nt]);
            }
        __syncthreads();
    }

    float inv[4];
#pragma unroll
    for (int r = 0; r < 4; r++) {
        float t = lsum[r];
        t += __shfl_xor(t, 1, 64);
        t += __shfl_xor(t, 2, 64);
        t += __shfl_xor(t, 4, 64);
        t += __shfl_xor(t, 8, 64);
        inv[r] = 1.0f / t;
    }
    const int b = bh >> 4, h = bh & 15;
#pragma unroll
    for (int nt = 0; nt < 4; nt++)
#pragma unroll
        for (int r = 0; r < 4; r++) {
            int qq = q0w + g * 4 + r, d = nt * 16 + l16;
            Y[((size_t)(b * Tt + qq)) * DIMc + h * 64 + d] = f2bf(o[nt][r] * inv[r]);
        }
}

// ---------------------------------------------------------------------------
// Kernel 3: out = Y @ W_proj (M=4096,N=1024,K=1024), fp32 out. 128x128 tile.
// A (bf16) staged via global_load_lds w16.
// ---------------------------------------------------------------------------
__global__ __launch_bounds__(256) void proj(
    const short* __restrict__ Yb, const float* __restrict__ W, float* __restrict__ O)
{
    __shared__ __align__(16) short As[128][32];
    __shared__ __align__(16) short Bs[128][32];
    const int bm = blockIdx.x, bn = blockIdx.y;
    const int tid = threadIdx.x;
    const int wv = tid >> 6, lane = tid & 63, g = lane >> 4, l16 = lane & 15;
    const int wr = wv >> 1, wc = wv & 1;

    f32x4 acc[4][4];
#pragma unroll
    for (int i = 0; i < 4; i++)
#pragma unroll
        for (int j = 0; j < 4; j++) acc[i][j] = (f32x4){0.f, 0.f, 0.f, 0.f};

    for (int k0 = 0; k0 < 1024; k0 += 32) {
#pragma unroll
        for (int i = 0; i < 2; i++) {              // A 128x32 bf16 via global_load_lds
            int p = tid + i * 256;
            int r = p >> 2, c = (p & 3) << 3;
            gl_lds16(Yb + (size_t)(bm * 128 + r) * 1024 + k0 + c, &As[r][c]);
        }
#pragma unroll
        for (int i = 0; i < 4; i++) {              // B 32x128 fp32->bf16 (transpose)
            int p = tid + i * 256;
            int kk = p >> 5, c = (p & 31) << 2;
            float4 v = *(const float4*)(W + (size_t)(k0 + kk) * 1024 + bn * 128 + c);
            Bs[c + 0][kk] = f2bf(v.x); Bs[c + 1][kk] = f2bf(v.y);
            Bs[c + 2][kk] = f2bf(v.z); Bs[c + 3][kk] = f2bf(v.w);
        }
        __syncthreads();
        short8 af[4], bfr[4];
#pragma unroll
        for (int mt = 0; mt < 4; mt++) af[mt]  = *(const short8*)&As[wr * 64 + mt * 16 + l16][g * 8];
#pragma unroll
        for (int nt = 0; nt < 4; nt++) bfr[nt] = *(const short8*)&Bs[wc * 64 + nt * 16 + l16][g * 8];
#pragma unroll
        for (int mt = 0; mt < 4; mt++)
#pragma unroll
            for (int nt = 0; nt < 4; nt++) acc[mt][nt] = mfma16(af[mt], bfr[nt], acc[mt][nt]);
        __syncthreads();
    }

#pragma unroll
    for (int mt = 0; mt < 4; mt++)
#pragma unroll
        for (int nt = 0; nt < 4; nt++)
#pragma unroll
            for (int r = 0; r < 4; r++) {
                int m = bm * 128 + wr * 64 + mt * 16 + g * 4 + r;
                int n = bn * 128 + wc * 64 + nt * 16 + l16;
                O[(size_t)m * 1024 + n] = acc[mt][nt][r];
            }
}

// ---------------------------------------------------------------------------
extern "C" void kernel_launch(void* const* d_in, const int* in_sizes, int n_in,
                              void* d_out, int out_size, void* d_ws, size_t ws_size,
                              hipStream_t stream)
{
    const float* x     = (const float*)d_in[0];
    const float* sn    = (const float*)d_in[1];
    const float* cs    = (const float*)d_in[2];
    const float* wqkv  = (const float*)d_in[3];
    const float* wproj = (const float*)d_in[4];
    float* out = (float*)d_out;

    char* ws = (char*)d_ws;
    const size_t SEG = (size_t)Bb * NHh * Tt * HDd * sizeof(short);  // 8 MB
    short* q  = (short*)(ws);
    short* k  = (short*)(ws + SEG);
    short* vt = (short*)(ws + 2 * SEG);
    short* y  = (short*)(ws + 3 * SEG);

    qkv_rope<<<dim3(32, 24), 256, 0, stream>>>(x, wqkv, sn, cs, q, k, vt);
    attn<<<dim3(Tt / 64, Bb * NHh), 256, 0, stream>>>(q, k, vt, y);
    proj<<<dim3(32, 8), 256, 0, stream>>>(y, wproj, out);
}

// Round 3
// 204.095 us; speedup vs baseline: 2.8783x; 2.0773x over previous
//
#include <hip/hip_runtime.h>

// MHA forward: B=2, T=2048, DIM=1024, NH=16, HD=64
// [convX, convT x2]  -> ws{Xb bf16 [M][K], Wqkv^T bf16 [3072][1024], Wproj^T bf16 [1024][1024]}
// [qkv GEMM m97-style + RoPE] -> ws{Q,K bf16 [B,NH,T,HD], V^T bf16 [B,NH,HD,T]}
// [flash attn, LDS dbuf] -> ws{Y bf16 [B,T,DIM]}
// [proj GEMM m97-style] -> d_out fp32

typedef float  f32x4  __attribute__((ext_vector_type(4)));
typedef __bf16 bf16x8 __attribute__((ext_vector_type(8)));
typedef short  short8 __attribute__((ext_vector_type(8)));

#define Bb   2
#define Tt   2048
#define DIMc 1024
#define NHh  16
#define HDd  64

__device__ __forceinline__ short f2bf(float f) {
    unsigned u = __builtin_bit_cast(unsigned, f);
    u += 0x7fffu + ((u >> 16) & 1u);          // RNE
    return (short)(u >> 16);
}

__device__ __forceinline__ f32x4 mfma16(short8 a, short8 b, f32x4 c) {
    return __builtin_amdgcn_mfma_f32_16x16x32_bf16(
        __builtin_bit_cast(bf16x8, a), __builtin_bit_cast(bf16x8, b), c, 0, 0, 0);
}

__device__ __forceinline__ void gl_lds16(const void* g, void* l) {
    __builtin_amdgcn_global_load_lds(
        (const __attribute__((address_space(1))) unsigned int*)g,
        (__attribute__((address_space(3))) unsigned int*)l, 16, 0, 0);
}

// ---------------------------------------------------------------------------
// convX: fp32 -> bf16 elementwise, 8 elems/thread.
// ---------------------------------------------------------------------------
__global__ __launch_bounds__(256) void convX(const float* __restrict__ X,
                                             short* __restrict__ Xb)
{
    size_t i = ((size_t)blockIdx.x * 256 + threadIdx.x) * 8;
    float4 a = *(const float4*)(X + i);
    float4 b = *(const float4*)(X + i + 4);
    short8 s;
    s[0] = f2bf(a.x); s[1] = f2bf(a.y); s[2] = f2bf(a.z); s[3] = f2bf(a.w);
    s[4] = f2bf(b.x); s[5] = f2bf(b.y); s[6] = f2bf(b.z); s[7] = f2bf(b.w);
    *(short8*)(Xb + i) = s;
}

// ---------------------------------------------------------------------------
// convT: W fp32 [K=1024][N] -> Wt bf16 [N][1024]. 64x64 LDS tile transpose.
// ---------------------------------------------------------------------------
__global__ __launch_bounds__(256) void convT(const float* __restrict__ W,
                                             short* __restrict__ Wt, int N)
{
    __shared__ float L[64][65];
    const int kb = blockIdx.x * 64, nb = blockIdx.y * 64;
    const int tid = threadIdx.x;
#pragma unroll
    for (int it = 0; it < 4; it++) {
        int kk = it * 16 + (tid >> 4), c = (tid & 15) * 4;
        float4 v = *(const float4*)(W + (size_t)(kb + kk) * N + nb + c);
        L[c + 0][kk] = v.x; L[c + 1][kk] = v.y;
        L[c + 2][kk] = v.z; L[c + 3][kk] = v.w;
    }
    __syncthreads();
#pragma unroll
    for (int it = 0; it < 2; it++) {
        int n = it * 32 + (tid >> 3), ks = (tid & 7) * 8;
        short8 s;
#pragma unroll
        for (int j = 0; j < 8; j++) s[j] = f2bf(L[n][ks + j]);
        *(short8*)(Wt + (size_t)(nb + n) * 1024 + kb + ks) = s;
    }
}

// ---------------------------------------------------------------------------
// qkv GEMM: C = Xb @ Wqkv (via Wt [3072][1024]), M=4096,N=3072,K=1024.
// m97 structure: 128x128 tile, BK=32, both operands via global_load_lds w16.
// Fused RoPE epilogue; V written transposed.
// ---------------------------------------------------------------------------
__global__ __launch_bounds__(256) void qkv_rope(
    const short* __restrict__ A, const short* __restrict__ Bt,
    const float* __restrict__ Sn, const float* __restrict__ Cs,
    short* __restrict__ Qo, short* __restrict__ Ko, short* __restrict__ Vt)
{
    __shared__ __align__(16) short As[128][32];
    __shared__ __align__(16) short Bs[128][32];
    const int bm = blockIdx.x, bn = blockIdx.y;
    const int tid = threadIdx.x;
    const int wv = tid >> 6, lane = tid & 63, g = lane >> 4, l16 = lane & 15;
    const int wr = wv >> 1, wc = wv & 1;

    f32x4 acc[4][4];
#pragma unroll
    for (int i = 0; i < 4; i++)
#pragma unroll
        for (int j = 0; j < 4; j++) acc[i][j] = (f32x4){0.f, 0.f, 0.f, 0.f};

    const int rA = tid >> 2, cA = (tid & 3) << 3;     // staging coords (per 256-chunk)
    for (int k0 = 0; k0 < 1024; k0 += 32) {
#pragma unroll
        for (int i = 0; i < 2; i++)
            gl_lds16(A + (size_t)(bm * 128 + i * 64 + rA) * 1024 + k0 + cA,
                     &As[i * 64 + rA][cA]);
#pragma unroll
        for (int i = 0; i < 2; i++)
            gl_lds16(Bt + (size_t)(bn * 128 + i * 64 + rA) * 1024 + k0 + cA,
                     &Bs[i * 64 + rA][cA]);
        __syncthreads();
        short8 af[4], bfr[4];
#pragma unroll
        for (int mt = 0; mt < 4; mt++) af[mt]  = *(const short8*)&As[wr * 64 + mt * 16 + l16][g * 8];
#pragma unroll
        for (int nt = 0; nt < 4; nt++) bfr[nt] = *(const short8*)&Bs[wc * 64 + nt * 16 + l16][g * 8];
#pragma unroll
        for (int mt = 0; mt < 4; mt++)
#pragma unroll
            for (int nt = 0; nt < 4; nt++) acc[mt][nt] = mfma16(af[mt], bfr[nt], acc[mt][nt]);
        __syncthreads();
    }

#pragma unroll
    for (int mt = 0; mt < 4; mt++)
#pragma unroll
        for (int nt = 0; nt < 4; nt++)
#pragma unroll
            for (int r = 0; r < 4; r++) {
                int m = bm * 128 + wr * 64 + mt * 16 + g * 4 + r;
                int n = bn * 128 + wc * 64 + nt * 16 + l16;
                float val = acc[mt][nt][r];
                float partner = __shfl_xor(val, 1, 64);
                int b = m >> 11, t = m & 2047;
                int sec = n >> 10, nn = n & 1023;
                int h = nn >> 6, d = nn & 63;
                if (sec == 2) {
                    Vt[(((size_t)(b * 16 + h) * 64 + d) << 11) + t] = f2bf(val);
                } else {
                    float sv = Sn[t * 64 + d], cv = Cs[t * 64 + d];
                    float ro = (d & 1) ? fmaf(val, cv, partner * sv)
                                       : fmaf(val, cv, -partner * sv);
                    short* dst = (sec == 0) ? Qo : Ko;
                    dst[(((size_t)(b * 16 + h) << 11) + t) * 64 + d] = f2bf(ro);
                }
            }
}

// ---------------------------------------------------------------------------
// Kernel 2: causal flash attention (unchanged from round 2 — verified).
// ---------------------------------------------------------------------------
__global__ __launch_bounds__(256, 4) void attn(
    const short* __restrict__ Q, const short* __restrict__ K,
    const short* __restrict__ V, short* __restrict__ Y)
{
    __shared__ __align__(16) short Ks[2][64][64];
    __shared__ __align__(16) short Vs[2][64][64];
    __shared__ __align__(16) short Pl[4][16][64];

    const int id = blockIdx.y * gridDim.x + blockIdx.x;
    const int bh = id >> 5;
    const int qi = ((id & 31) + ((id >> 8) << 3)) & 31;
    const int tid = threadIdx.x, wv = tid >> 6, lane = tid & 63;
    const int g = lane >> 4, l16 = lane & 15;
    const int q0w = qi * 64 + wv * 16;
    const short* Qb = Q + (size_t)bh * Tt * 64;
    const short* Kb = K + (size_t)bh * Tt * 64;
    const short* Vb = V + (size_t)bh * 64 * Tt;

    const int rj = lane >> 3, cc = lane & 7, gc = cc ^ rj;

    auto stage = [&](int s, int buf) {
        int k0s = s * 64;
#pragma unroll
        for (int j = 0; j < 2; j++) {
            int row = wv * 16 + j * 8 + rj;
            gl_lds16(Kb + (size_t)(k0s + row) * 64 + gc * 8, &Ks[buf][row][cc << 3]);
        }
#pragma unroll
        for (int j = 0; j < 2; j++) {
            int row = wv * 16 + j * 8 + rj;
            gl_lds16(Vb + (size_t)row * Tt + k0s + gc * 8, &Vs[buf][row][cc << 3]);
        }
    };

    short8 qf[2];
#pragma unroll
    for (int ss = 0; ss < 2; ss++)
        qf[ss] = *(const short8*)(Qb + (size_t)(q0w + l16) * 64 + ss * 32 + g * 8);

    f32x4 o[4];
#pragma unroll
    for (int nt = 0; nt < 4; nt++) o[nt] = (f32x4){0.f, 0.f, 0.f, 0.f};
    float lsum[4] = {0.f, 0.f, 0.f, 0.f};

    const int nsteps = qi + 1;
    const int sw = l16 & 7;

    stage(0, 0);
    __syncthreads();

    for (int s = 0; s < nsteps; ++s) {
        if (s + 1 < nsteps) stage(s + 1, (s + 1) & 1);
        const int kb = s & 1, k0 = s * 64;

        f32x4 S[4];
#pragma unroll
        for (int t = 0; t < 4; t++) {
            S[t] = (f32x4){0.f, 0.f, 0.f, 0.f};
#pragma unroll
            for (int ss = 0; ss < 2; ss++) {
                short8 kf = *(const short8*)&Ks[kb][t * 16 + l16][((ss * 4 + g) ^ sw) << 3];
                S[t] = mfma16(qf[ss], kf, S[t]);
            }
        }

        float p[4][4];
        if (s < nsteps - 1) {
#pragma unroll
            for (int t = 0; t < 4; t++)
#pragma unroll
                for (int r = 0; r < 4; r++)
                    p[t][r] = __expf(fmaf(S[t][r], 0.125f, -10.f));
        } else {
#pragma unroll
            for (int t = 0; t < 4; t++)
#pragma unroll
                for (int r = 0; r < 4; r++) {
                    int key = k0 + t * 16 + l16, qq = q0w + g * 4 + r;
                    p[t][r] = (key <= qq) ? __expf(fmaf(S[t][r], 0.125f, -10.f)) : 0.f;
                }
        }
#pragma unroll
        for (int r = 0; r < 4; r++)
            lsum[r] += (p[0][r] + p[1][r]) + (p[2][r] + p[3][r]);

#pragma unroll
        for (int t = 0; t < 4; t++)
#pragma unroll
            for (int r = 0; r < 4; r++) {
                int row = g * 4 + r, c = t * 16 + l16;
                Pl[wv][row][(((c >> 3) ^ (row & 7)) << 3) | (c & 7)] = f2bf(p[t][r]);
            }
        asm volatile("" ::: "memory");
        short8 pf[2];
#pragma unroll
        for (int ks = 0; ks < 2; ks++)
            pf[ks] = *(const short8*)&Pl[wv][l16][((ks * 4 + g) ^ sw) << 3];
#pragma unroll
        for (int nt = 0; nt < 4; nt++)
#pragma unroll
            for (int ks = 0; ks < 2; ks++) {
                short8 vf = *(const short8*)&Vs[kb][nt * 16 + l16][((ks * 4 + g) ^ sw) << 3];
                o[nt] = mfma16(pf[ks], vf, o[nt]);
            }
        __syncthreads();
    }

    float inv[4];
#pragma unroll
    for (int r = 0; r < 4; r++) {
        float t = lsum[r];
        t += __shfl_xor(t, 1, 64);
        t += __shfl_xor(t, 2, 64);
        t += __shfl_xor(t, 4, 64);
        t += __shfl_xor(t, 8, 64);
        inv[r] = 1.0f / t;
    }
    const int b = bh >> 4, h = bh & 15;
#pragma unroll
    for (int nt = 0; nt < 4; nt++)
#pragma unroll
        for (int r = 0; r < 4; r++) {
            int qq = q0w + g * 4 + r, d = nt * 16 + l16;
            Y[((size_t)(b * Tt + qq)) * DIMc + h * 64 + d] = f2bf(o[nt][r] * inv[r]);
        }
}

// ---------------------------------------------------------------------------
// proj GEMM: out = Y @ Wproj (via Wt [1024][1024]), fp32 out. m97 structure.
// ---------------------------------------------------------------------------
__global__ __launch_bounds__(256) void proj(
    const short* __restrict__ A, const short* __restrict__ Bt, float* __restrict__ O)
{
    __shared__ __align__(16) short As[128][32];
    __shared__ __align__(16) short Bs[128][32];
    const int bm = blockIdx.x, bn = blockIdx.y;
    const int tid = threadIdx.x;
    const int wv = tid >> 6, lane = tid & 63, g = lane >> 4, l16 = lane & 15;
    const int wr = wv >> 1, wc = wv & 1;

    f32x4 acc[4][4];
#pragma unroll
    for (int i = 0; i < 4; i++)
#pragma unroll
        for (int j = 0; j < 4; j++) acc[i][j] = (f32x4){0.f, 0.f, 0.f, 0.f};

    const int rA = tid >> 2, cA = (tid & 3) << 3;
    for (int k0 = 0; k0 < 1024; k0 += 32) {
#pragma unroll
        for (int i = 0; i < 2; i++)
            gl_lds16(A + (size_t)(bm * 128 + i * 64 + rA) * 1024 + k0 + cA,
                     &As[i * 64 + rA][cA]);
#pragma unroll
        for (int i = 0; i < 2; i++)
            gl_lds16(Bt + (size_t)(bn * 128 + i * 64 + rA) * 1024 + k0 + cA,
                     &Bs[i * 64 + rA][cA]);
        __syncthreads();
        short8 af[4], bfr[4];
#pragma unroll
        for (int mt = 0; mt < 4; mt++) af[mt]  = *(const short8*)&As[wr * 64 + mt * 16 + l16][g * 8];
#pragma unroll
        for (int nt = 0; nt < 4; nt++) bfr[nt] = *(const short8*)&Bs[wc * 64 + nt * 16 + l16][g * 8];
#pragma unroll
        for (int mt = 0; mt < 4; mt++)
#pragma unroll
            for (int nt = 0; nt < 4; nt++) acc[mt][nt] = mfma16(af[mt], bfr[nt], acc[mt][nt]);
        __syncthreads();
    }

#pragma unroll
    for (int mt = 0; mt < 4; mt++)
#pragma unroll
        for (int nt = 0; nt < 4; nt++)
#pragma unroll
            for (int r = 0; r < 4; r++) {
                int m = bm * 128 + wr * 64 + mt * 16 + g * 4 + r;
                int n = bn * 128 + wc * 64 + nt * 16 + l16;
                O[(size_t)m * 1024 + n] = acc[mt][nt][r];
            }
}

// ---------------------------------------------------------------------------
extern "C" void kernel_launch(void* const* d_in, const int* in_sizes, int n_in,
                              void* d_out, int out_size, void* d_ws, size_t ws_size,
                              hipStream_t stream)
{
    const float* x     = (const float*)d_in[0];
    const float* sn    = (const float*)d_in[1];
    const float* cs    = (const float*)d_in[2];
    const float* wqkv  = (const float*)d_in[3];
    const float* wproj = (const float*)d_in[4];
    float* out = (float*)d_out;

    char* ws = (char*)d_ws;
    const size_t MB = 1024 * 1024;
    short* q   = (short*)(ws);            // 8 MB
    short* k   = (short*)(ws + 8  * MB);  // 8 MB
    short* vt  = (short*)(ws + 16 * MB);  // 8 MB
    short* y   = (short*)(ws + 24 * MB);  // 8 MB
    short* xb  = (short*)(ws + 32 * MB);  // 8 MB
    short* wqt = (short*)(ws + 40 * MB);  // 6 MB
    short* wpt = (short*)(ws + 46 * MB);  // 2 MB

    convX<<<2048, 256, 0, stream>>>(x, xb);
    convT<<<dim3(16, 48), 256, 0, stream>>>(wqkv, wqt, 3072);
    convT<<<dim3(16, 16), 256, 0, stream>>>(wproj, wpt, 1024);
    qkv_rope<<<dim3(32, 24), 256, 0, stream>>>(xb, wqt, sn, cs, q, k, vt);
    attn<<<dim3(Tt / 64, Bb * NHh), 256, 0, stream>>>(q, k, vt, y);
    proj<<<dim3(32, 8), 256, 0, stream>>>(y, wpt, out);
}